// Round 5
// baseline (2187.694 us; speedup 1.0000x reference)
//
#include <hip/hip_runtime.h>

// ---------------------------------------------------------------------------
// EdgeTransition — Round 10: 2 blocks/CU for all gemms.
//  - gemm0/gemm1: LDS 80KB = A dbuf (2x16K) + B single (48K); 2 barriers/kt;
//    biases/residual aux read direct from global in epilogue; epilogue repack
//    in 4 wave-private scratch rounds aliasing staging LDS after final barrier.
//  - gemmF: shfl-based LayerNorm (no 67KB rep buffer) -> 68KB LDS.
//  - Rationale: R9 ran 1 block/CU; every __syncthreads vmcnt-drain was a
//    full-CU stall. Co-resident second block covers it (m114 overlap).
// Numerics: bf16x3 split (Ah*Wh + Ah*Wl + Al*Wh), rel err ~1e-4.
// ---------------------------------------------------------------------------

typedef short sv8 __attribute__((ext_vector_type(8)));   // 8 bf16 (4 VGPR)
typedef float f32x4 __attribute__((ext_vector_type(4))); // MFMA acc

union F8U { float4 v4[2]; float f[8]; };

__device__ __forceinline__ void async_cp16(const void* g, void* l) {
  __builtin_amdgcn_global_load_lds(
      (const __attribute__((address_space(1))) void*)g,
      (__attribute__((address_space(3))) void*)l, 16, 0, 0);
}

// truncation split: hi = top16(f), lo = bf16(f - hi)
__device__ __forceinline__ void split8(const float* v, sv8& hi, sv8& lo) {
#pragma unroll
  for (int i = 0; i < 8; i++) {
    unsigned u = __float_as_uint(v[i]);
    hi[i] = (short)(u >> 16);
    float fl = v[i] - __uint_as_float(u & 0xFFFF0000u);
    lo[i] = (short)(__float_as_uint(fl) >> 16);
  }
}

// ---------------------------------------------------------------------------
// pre-kernels: nb, Pb, Qm
// ---------------------------------------------------------------------------
__global__ void node_proj(const float* __restrict__ node,
                          const float* __restrict__ w,
                          const float* __restrict__ b,
                          float* __restrict__ nb) {
  __shared__ float sn[256];
  int i = blockIdx.x;
  int t = threadIdx.x;  // 128
  sn[t] = node[i * 256 + t];
  sn[t + 128] = node[i * 256 + t + 128];
  __syncthreads();
  float acc = b[t];
  for (int k = 0; k < 256; k++) acc += sn[k] * w[k * 128 + t];
  nb[i * 128 + t] = acc;
}

__global__ void pq_proj(const float* __restrict__ nb,
                        const float* __restrict__ w0,
                        const float* __restrict__ b0,
                        float* __restrict__ Pb, float* __restrict__ Qm) {
  __shared__ float sn[128];
  const int j = blockIdx.x, t = threadIdx.x;  // 384
  if (t < 128) sn[t] = nb[j * 128 + t];
  __syncthreads();
  float ap = b0[t], aq = 0.0f;
  for (int k = 0; k < 128; k++) {
    const float nk = sn[k];
    ap += nk * w0[(128 + k) * 384 + t];
    aq += nk * w0[(256 + k) * 384 + t];
  }
  Pb[j * 384 + t] = ap;
  Qm[j * 384 + t] = aq;
}

// ---------------------------------------------------------------------------
// pack W (K x N row-major, f32) -> PK split tiles [nt][kt][2][1KB]
// tile (nt,kt): lane l holds B[k = kt*32+(l>>4)*8+i][n = nt*16+(l&15)]
// ---------------------------------------------------------------------------
__global__ void pack_b(const float* __restrict__ W, int N, int NKT,
                       float* __restrict__ dst) {
  const int nt = blockIdx.x, kt = blockIdx.y, l = threadIdx.x;  // 64 thr
  const int n = nt * 16 + (l & 15);
  const int k0 = kt * 32 + ((l >> 4) * 8);
  float v[8];
#pragma unroll
  for (int i = 0; i < 8; i++) v[i] = W[(size_t)(k0 + i) * N + n];
  sv8 hi, lo;
  split8(v, hi, lo);
  char* base = (char*)dst + (size_t)((nt * NKT + kt) * 2) * 1024;
  *(sv8*)(base + l * 16) = hi;
  *(sv8*)(base + 1024 + l * 16) = lo;
}

// ---------------------------------------------------------------------------
// staging helpers — LDS dest wave-uniform; HW adds lane*16.
// ---------------------------------------------------------------------------
__device__ __forceinline__ void stage_e(const float* E, long mblk, int kt,
                                        char* dst, int wid, int lane) {
#pragma unroll
  for (int q = 0; q < 2; q++) {
    int c = wid * 2 + q;  // 0..15
    int row = c * 8 + (lane >> 3);
    int kb = ((lane & 7) * 16) ^ ((row & 7) << 4);
    const char* src =
        (const char*)E + (size_t)(mblk + row) * 512 + (size_t)kt * 128 + kb;
    async_cp16(src, dst + c * 1024);
  }
}

template <int PW>
__device__ __forceinline__ void stage_apk(const float* Apk, long mt0, int NKT,
                                          int kt, char* dst, int wid,
                                          int lane) {
#pragma unroll
  for (int q = 0; q < PW; q++) {
    int idx = wid * PW + q;  // mt*2+split
    int mt = idx >> 1, sp = idx & 1;
    const char* src = (const char*)Apk +
                      (size_t)(((mt0 + mt) * NKT + kt) * 2 + sp) * 1024 +
                      lane * 16;
    async_cp16(src, dst + idx * 1024);
  }
}

template <int PW>
__device__ __forceinline__ void stage_bpk(const float* Bpk, int NKT, int kt,
                                          char* dst, int wid, int lane) {
#pragma unroll
  for (int q = 0; q < PW; q++) {
    int idx = wid * PW + q;  // nt*2+split
    int nt = idx >> 1, sp = idx & 1;
    const char* src = (const char*)Bpk +
                      (size_t)((nt * NKT + kt) * 2 + sp) * 1024 + lane * 16;
    async_cp16(src, dst + idx * 1024);
  }
}

#define MFMA __builtin_amdgcn_mfma_f32_16x16x32_bf16

// ---------------------------------------------------------------------------
// gemm0: C0pk = relu(E@W0pk + Pb[i] + Qm[j])   [128 x 384 per block]
// LDS: A dbuf 0/16K ; B single @32768 (48K). Total 80K -> 2 blocks/CU.
// ---------------------------------------------------------------------------
__global__ __launch_bounds__(512, 4) void gemm0_k(
    const float* __restrict__ E, const float* __restrict__ W0pk,
    const float* __restrict__ Pb, const float* __restrict__ Qm,
    float* __restrict__ C0pk, long m0) {
  __shared__ __align__(16) char sm[81920];
  const int t = threadIdx.x, lane = t & 63, wid = t >> 6;
  const int rb = wid >> 2, cb = wid & 3;
  const long mblk = m0 + (long)blockIdx.x * 128;
  const int i_node = (int)(mblk >> 9);

  f32x4 acc[4][6] = {};

  stage_e(E, mblk, 0, sm, wid, lane);
  stage_bpk<6>(W0pk, 4, 0, sm + 32768, wid, lane);
  __syncthreads();

  for (int kt = 0; kt < 4; kt++) {
    // prefetch next A tile into the other A buffer (overlaps reads+MFMA)
    if (kt < 3) stage_e(E, mblk, kt + 1, sm + ((kt + 1) & 1) * 16384, wid, lane);

    const char* sA = sm + (kt & 1) * 16384;
    const char* sB = sm + 32768;
    sv8 ah[4], al[4], bh[6], bl[6];
#pragma unroll
    for (int rt = 0; rt < 4; rt++) {
      int row = rb * 64 + rt * 16 + (lane & 15);
      int c0 = (lane >> 4) * 32;
      F8U v;
      v.v4[0] = *(const float4*)(sA + row * 128 + (c0 ^ ((row & 7) << 4)));
      v.v4[1] =
          *(const float4*)(sA + row * 128 + ((c0 + 16) ^ ((row & 7) << 4)));
      split8(v.f, ah[rt], al[rt]);
    }
#pragma unroll
    for (int nt = 0; nt < 6; nt++) {
      int gnt = cb * 6 + nt;
      bh[nt] = *(const sv8*)(sB + gnt * 2048 + lane * 16);
      bl[nt] = *(const sv8*)(sB + gnt * 2048 + 1024 + lane * 16);
    }
#pragma unroll
    for (int rt = 0; rt < 4; rt++)
#pragma unroll
      for (int nt = 0; nt < 6; nt++) {
        acc[rt][nt] = MFMA(ah[rt], bh[nt], acc[rt][nt], 0, 0, 0);
        acc[rt][nt] = MFMA(ah[rt], bl[nt], acc[rt][nt], 0, 0, 0);
        acc[rt][nt] = MFMA(al[rt], bh[nt], acc[rt][nt], 0, 0, 0);
      }
    __syncthreads();  // all waves done reading A(kt), B(kt)
    if (kt < 3) {
      stage_bpk<6>(W0pk, 4, kt + 1, sm + 32768, wid, lane);  // overwrite B
      __syncthreads();  // B(kt+1) + A(kt+1) staged
    }
  }

  // ---- epilogue: 4 wave-private scratch rounds (aliases staging LDS) ----
  float* scr = (float*)(sm + wid * 10240);  // 32x52 f32 = 6656 B per wave
  const int row32r = lane & 31;
#pragma unroll
  for (int h = 0; h < 2; h++) {
#pragma unroll
    for (int rh = 0; rh < 2; rh++) {
#pragma unroll
      for (int rt2 = 0; rt2 < 2; rt2++)
#pragma unroll
        for (int ntl = 0; ntl < 3; ntl++)
#pragma unroll
          for (int rg = 0; rg < 4; rg++) {
            int row32 = rt2 * 16 + (lane >> 4) * 4 + rg;
            scr[row32 * 52 + ntl * 16 + (lane & 15)] =
                acc[rh * 2 + rt2][h * 3 + ntl][rg];
          }
      // wave-private: no barrier needed (same wave writes then reads)
      const int rowb = rb * 64 + rh * 32 + row32r;
      const long m = mblk + rowb;
      const int j = (int)(m & 511);
#pragma unroll
      for (int qq = 0; qq < 3; qq++) {
        const int cloc = ((lane >> 5) * 3 + qq) * 8;
        const int colg = cb * 96 + h * 48 + cloc;
        F8U v;
        v.v4[0] = *(float4*)(scr + row32r * 52 + cloc);
        v.v4[1] = *(float4*)(scr + row32r * 52 + cloc + 4);
        F8U pv, qv;
        pv.v4[0] = *(const float4*)(Pb + (size_t)i_node * 384 + colg);
        pv.v4[1] = *(const float4*)(Pb + (size_t)i_node * 384 + colg + 4);
        qv.v4[0] = *(const float4*)(Qm + (size_t)j * 384 + colg);
        qv.v4[1] = *(const float4*)(Qm + (size_t)j * 384 + colg + 4);
#pragma unroll
        for (int i = 0; i < 8; i++)
          v.f[i] = fmaxf(v.f[i] + pv.f[i] + qv.f[i], 0.0f);
        sv8 hi, lo;
        split8(v.f, hi, lo);
        const long mt = (long)blockIdx.x * 8 + (rowb >> 4);
        const int lane2 = (rowb & 15) | (((colg >> 3) & 3) << 4);
        char* base =
            (char*)C0pk + (size_t)((mt * 12 + (colg >> 5)) * 2) * 1024;
        *(sv8*)(base + lane2 * 16) = hi;
        *(sv8*)(base + 1024 + lane2 * 16) = lo;
      }
    }
  }
}

// ---------------------------------------------------------------------------
// gemm1: A2pk = relu(C0pk@W1pk + b1) + [E | nb_i | nb_j]
// Same 80KB structure as gemm0.
// ---------------------------------------------------------------------------
__global__ __launch_bounds__(512, 4) void gemm1_k(
    const float* __restrict__ C0pk, const float* __restrict__ W1pk,
    const float* __restrict__ b1, const float* __restrict__ E,
    const float* __restrict__ nb, float* __restrict__ A2pk, long m0) {
  __shared__ __align__(16) char sm[81920];
  const int t = threadIdx.x, lane = t & 63, wid = t >> 6;
  const int rb = wid >> 2, cb = wid & 3;
  const long mblk = m0 + (long)blockIdx.x * 128;
  const int i_node = (int)(mblk >> 9);
  const long mt0 = (long)blockIdx.x * 8;

  f32x4 acc[4][6] = {};

  stage_apk<2>(C0pk, mt0, 12, 0, sm, wid, lane);
  stage_bpk<6>(W1pk, 12, 0, sm + 32768, wid, lane);
  __syncthreads();

  for (int kt = 0; kt < 12; kt++) {
    if (kt < 11)
      stage_apk<2>(C0pk, mt0, 12, kt + 1, sm + ((kt + 1) & 1) * 16384, wid,
                   lane);

    const char* sA = sm + (kt & 1) * 16384;
    const char* sB = sm + 32768;
    sv8 ah[4], al[4], bh[6], bl[6];
#pragma unroll
    for (int rt = 0; rt < 4; rt++) {
      int mtl = rb * 4 + rt;
      ah[rt] = *(const sv8*)(sA + mtl * 2048 + lane * 16);
      al[rt] = *(const sv8*)(sA + mtl * 2048 + 1024 + lane * 16);
    }
#pragma unroll
    for (int nt = 0; nt < 6; nt++) {
      int gnt = cb * 6 + nt;
      bh[nt] = *(const sv8*)(sB + gnt * 2048 + lane * 16);
      bl[nt] = *(const sv8*)(sB + gnt * 2048 + 1024 + lane * 16);
    }
#pragma unroll
    for (int rt = 0; rt < 4; rt++)
#pragma unroll
      for (int nt = 0; nt < 6; nt++) {
        acc[rt][nt] = MFMA(ah[rt], bh[nt], acc[rt][nt], 0, 0, 0);
        acc[rt][nt] = MFMA(ah[rt], bl[nt], acc[rt][nt], 0, 0, 0);
        acc[rt][nt] = MFMA(al[rt], bh[nt], acc[rt][nt], 0, 0, 0);
      }
    __syncthreads();
    if (kt < 11) {
      stage_bpk<6>(W1pk, 12, kt + 1, sm + 32768, wid, lane);
      __syncthreads();
    }
  }

  // ---- epilogue ----
  float* scr = (float*)(sm + wid * 10240);
  const int row32r = lane & 31;
#pragma unroll
  for (int h = 0; h < 2; h++) {
#pragma unroll
    for (int rh = 0; rh < 2; rh++) {
#pragma unroll
      for (int rt2 = 0; rt2 < 2; rt2++)
#pragma unroll
        for (int ntl = 0; ntl < 3; ntl++)
#pragma unroll
          for (int rg = 0; rg < 4; rg++) {
            int row32 = rt2 * 16 + (lane >> 4) * 4 + rg;
            scr[row32 * 52 + ntl * 16 + (lane & 15)] =
                acc[rh * 2 + rt2][h * 3 + ntl][rg];
          }
      const int rowb = rb * 64 + rh * 32 + row32r;
      const long m = mblk + rowb;
      const int j = (int)(m & 511);
#pragma unroll
      for (int qq = 0; qq < 3; qq++) {
        const int cloc = ((lane >> 5) * 3 + qq) * 8;
        const int colg = cb * 96 + h * 48 + cloc;
        F8U v;
        v.v4[0] = *(float4*)(scr + row32r * 52 + cloc);
        v.v4[1] = *(float4*)(scr + row32r * 52 + cloc + 4);
        F8U bv, hv;
        bv.v4[0] = *(const float4*)(b1 + colg);
        bv.v4[1] = *(const float4*)(b1 + colg + 4);
        if (colg < 128) {
          hv.v4[0] = *(const float4*)(E + (size_t)m * 128 + colg);
          hv.v4[1] = *(const float4*)(E + (size_t)m * 128 + colg + 4);
        } else if (colg < 256) {
          hv.v4[0] = *(const float4*)(nb + (size_t)i_node * 128 + (colg - 128));
          hv.v4[1] =
              *(const float4*)(nb + (size_t)i_node * 128 + (colg - 128) + 4);
        } else {
          hv.v4[0] = *(const float4*)(nb + (size_t)j * 128 + (colg - 256));
          hv.v4[1] = *(const float4*)(nb + (size_t)j * 128 + (colg - 256) + 4);
        }
#pragma unroll
        for (int i = 0; i < 8; i++)
          v.f[i] = fmaxf(v.f[i] + bv.f[i], 0.0f) + hv.f[i];
        sv8 hi, lo;
        split8(v.f, hi, lo);
        const long mt = (long)blockIdx.x * 8 + (rowb >> 4);
        const int lane2 = (rowb & 15) | (((colg >> 3) & 3) << 4);
        char* base =
            (char*)A2pk + (size_t)((mt * 12 + (colg >> 5)) * 2) * 1024;
        *(sv8*)(base + lane2 * 16) = hi;
        *(sv8*)(base + 1024 + lane2 * 16) = lo;
      }
    }
  }
}

// ---------------------------------------------------------------------------
// gemmF: out = LN(A2pk@Wfpk + bf)   [128 x 128 per block], 4 waves
// LDS: A dbuf 0/16K ; B dbuf 32K/48K ; aux @65536 (ln params + partials).
// Total ~68KB -> 2 blocks/CU. LN via 16-lane shfl + 2KB cross-wave exchange.
// ---------------------------------------------------------------------------
__global__ __launch_bounds__(256, 2) void gemmF_k(
    const float* __restrict__ A2pk, const float* __restrict__ Wfpk,
    const float* __restrict__ bfin, const float* __restrict__ lng,
    const float* __restrict__ lnb, float* __restrict__ out, long m0) {
  __shared__ __align__(16) char sm[69632];
  const int t = threadIdx.x, lane = t & 63, wid = t >> 6;
  const int rb = wid >> 1, cb = wid & 1;
  const long mblk = m0 + (long)blockIdx.x * 128;
  float* sG = (float*)(sm + 65536);   // 128 f32
  float* sB = sG + 128;               // 128 f32
  float* sBf = sG + 256;              // 128 f32
  float* sLN = sG + 384;              // 128 rows x 4 (s0,q0,s1,q1)
  if (t < 128) {
    sG[t] = lng[t];
    sB[t] = lnb[t];
    sBf[t] = bfin[t];
  }

  f32x4 acc[4][4] = {};
  const long mt0 = (long)blockIdx.x * 8;
  stage_apk<4>(A2pk, mt0, 12, 0, sm, wid, lane);
  stage_bpk<4>(Wfpk, 12, 0, sm + 32768, wid, lane);
  __syncthreads();

  for (int kt = 0; kt < 12; kt++) {
    const int buf = kt & 1;
    if (kt < 11) {
      stage_apk<4>(A2pk, mt0, 12, kt + 1, sm + (buf ^ 1) * 16384, wid, lane);
      stage_bpk<4>(Wfpk, 12, kt + 1, sm + 32768 + (buf ^ 1) * 16384, wid,
                   lane);
    }
    const char* sA = sm + buf * 16384;
    const char* sBt = sm + 32768 + buf * 16384;
    sv8 ah[4], al[4], bh[4], bl[4];
#pragma unroll
    for (int rt = 0; rt < 4; rt++) {
      int mtl = rb * 4 + rt;
      ah[rt] = *(const sv8*)(sA + mtl * 2048 + lane * 16);
      al[rt] = *(const sv8*)(sA + mtl * 2048 + 1024 + lane * 16);
    }
#pragma unroll
    for (int nt = 0; nt < 4; nt++) {
      int gnt = cb * 4 + nt;
      bh[nt] = *(const sv8*)(sBt + gnt * 2048 + lane * 16);
      bl[nt] = *(const sv8*)(sBt + gnt * 2048 + 1024 + lane * 16);
    }
#pragma unroll
    for (int rt = 0; rt < 4; rt++)
#pragma unroll
      for (int nt = 0; nt < 4; nt++) {
        acc[rt][nt] = MFMA(ah[rt], bh[nt], acc[rt][nt], 0, 0, 0);
        acc[rt][nt] = MFMA(ah[rt], bl[nt], acc[rt][nt], 0, 0, 0);
        acc[rt][nt] = MFMA(al[rt], bh[nt], acc[rt][nt], 0, 0, 0);
      }
    __syncthreads();
  }

  // ---- LN partial sums: per (rt,rg) row, reduce over nt + 16-lane group ----
#pragma unroll
  for (int rt = 0; rt < 4; rt++)
#pragma unroll
    for (int rg = 0; rg < 4; rg++) {
      float s = 0.0f, q = 0.0f;
#pragma unroll
      for (int nt = 0; nt < 4; nt++) {
        const int col = cb * 64 + nt * 16 + (lane & 15);
        const float v = acc[rt][nt][rg] + sBf[col];
        s += v;
        q += v * v;
      }
#pragma unroll
      for (int off = 1; off <= 8; off <<= 1) {
        s += __shfl_xor(s, off);
        q += __shfl_xor(q, off);
      }
      const int row = rb * 64 + rt * 16 + (lane >> 4) * 4 + rg;
      if ((lane & 15) == 0) {
        sLN[row * 4 + cb * 2 + 0] = s;
        sLN[row * 4 + cb * 2 + 1] = q;
      }
    }
  __syncthreads();

  // ---- normalize + store ----
#pragma unroll
  for (int rt = 0; rt < 4; rt++)
#pragma unroll
    for (int rg = 0; rg < 4; rg++) {
      const int row = rb * 64 + rt * 16 + (lane >> 4) * 4 + rg;
      const float s = sLN[row * 4 + 0] + sLN[row * 4 + 2];
      const float q = sLN[row * 4 + 1] + sLN[row * 4 + 3];
      const float mu = s * (1.0f / 128.0f);
      const float var = q * (1.0f / 128.0f) - mu * mu;
      const float rstd = rsqrtf(var + 1e-5f);
      float* op = out + (size_t)(mblk + row) * 128;
#pragma unroll
      for (int nt = 0; nt < 4; nt++) {
        const int col = cb * 64 + nt * 16 + (lane & 15);
        const float v = acc[rt][nt][rg] + sBf[col];
        op[col] = (v - mu) * rstd * sG[col] + sB[col];
      }
    }
}

// ---------------------------------------------------------------------------
// Round-7 fp32 fallback (last resort, known-green)
// ---------------------------------------------------------------------------
#define ROWS 32
#define PF 388
#define TM 8
union F4 { float4 v; float f[4]; };
union F2 { float2 v; float f[2]; };

__device__ __forceinline__ void stage_tile7(const float* __restrict__ g,
                                            float* l, int nchunk, int t) {
  const int lane = t & 63, wid = t >> 6;
  for (int c = wid; c < nchunk; c += 8)
    async_cp16(g + c * 256 + lane * 4, l + c * 256);
}

__device__ __forceinline__ void trunk_tile7(const float* __restrict__ src,
                                            int koff,
                                            const float* __restrict__ wt,
                                            int cA, int cB, int mr,
                                            float acc[TM][3]) {
  for (int kk = 0; kk < 16; kk += 4) {
    F4 a[TM];
#pragma unroll
    for (int r = 0; r < TM; r++)
      a[r].v = *(const float4*)(src + (mr + r) * PF + koff + kk);
#pragma unroll
    for (int ks = 0; ks < 4; ks++) {
      const float* wrow = wt + (kk + ks) * 384;
      F2 w2;
      w2.v = *(const float2*)(wrow + cA);
      const float w1 = wrow[cB];
#pragma unroll
      for (int r = 0; r < TM; r++) {
        const float ak = a[r].f[ks];
        acc[r][0] += ak * w2.f[0];
        acc[r][1] += ak * w2.f[1];
        acc[r][2] += ak * w1;
      }
    }
  }
}

__global__ __launch_bounds__(512, 1) void edge_fused_r7(
    const float* __restrict__ edge, const float* __restrict__ nbf,
    const float* __restrict__ Pb, const float* __restrict__ Qm,
    const float* __restrict__ w0, const float* __restrict__ w1,
    const float* __restrict__ b1v, const float* __restrict__ wf,
    const float* __restrict__ bfin, const float* __restrict__ lng,
    const float* __restrict__ lnb, float* __restrict__ out) {
  __shared__ __align__(16) float Abuf[ROWS * PF];
  __shared__ __align__(16) float Bbuf[ROWS * PF];
  __shared__ __align__(16) float Wt[2][16 * 384];
  __shared__ __align__(16) float snbi[128];

  const int t = threadIdx.x;
  const int ct = t & 63;
  const int g = t >> 8;
  const int mr = ((t >> 6) & 3) * TM;
  const int cA = g * 192 + 2 * ct;
  const int cB = g * 192 + 128 + ct;
  const int r0 = blockIdx.x * ROWS;
  const int i_node = r0 >> 9, j0 = r0 & 511;

  {
    const int row = t >> 4, q = t & 15;
    const float* ep = edge + (size_t)(r0 + row) * 128 + q * 8;
    float* ap = Abuf + row * PF + q * 8;
    *(float4*)(ap + 0) = *(const float4*)(ep + 0);
    *(float4*)(ap + 4) = *(const float4*)(ep + 4);
  }
  if (t < 32)
    *(float4*)(snbi + t * 4) = *(const float4*)(nbf + i_node * 128 + t * 4);

  stage_tile7(w0, Wt[0], 24, t);

  float acc[TM][3];
  {
    const float* pr = Pb + i_node * 384;
    F2 p2;
    p2.v = *(const float2*)(pr + cA);
    const float p1 = pr[cB];
#pragma unroll
    for (int r = 0; r < TM; r++) {
      const float* qr = Qm + (size_t)(j0 + mr + r) * 384;
      F2 q2;
      q2.v = *(const float2*)(qr + cA);
      acc[r][0] = p2.f[0] + q2.f[0];
      acc[r][1] = p2.f[1] + q2.f[1];
      acc[r][2] = p1 + qr[cB];
    }
  }

  for (int kt = 0; kt < 8; kt++) {
    __syncthreads();
    if (kt < 7) stage_tile7(w0 + (kt + 1) * 6144, Wt[(kt + 1) & 1], 24, t);
    trunk_tile7(Abuf, kt * 16, Wt[kt & 1], cA, cB, mr, acc);
  }

  stage_tile7(w1, Wt[0], 24, t);
#pragma unroll
  for (int r = 0; r < TM; r++) {
    float* dr = Bbuf + (mr + r) * PF;
    F2 e2;
    e2.f[0] = fmaxf(acc[r][0], 0.0f);
    e2.f[1] = fmaxf(acc[r][1], 0.0f);
    *(float2*)(dr + cA) = e2.v;
    dr[cB] = fmaxf(acc[r][2], 0.0f);
  }

  {
    F2 c2;
    c2.v = *(const float2*)(b1v + cA);
    const float c1 = b1v[cB];
#pragma unroll
    for (int r = 0; r < TM; r++) {
      acc[r][0] = c2.f[0];
      acc[r][1] = c2.f[1];
      acc[r][2] = c1;
    }
  }

  for (int kt = 0; kt < 24; kt++) {
    __syncthreads();
    if (kt < 23) stage_tile7(w1 + (kt + 1) * 6144, Wt[(kt + 1) & 1], 24, t);
    trunk_tile7(Bbuf, kt * 16, Wt[kt & 1], cA, cB, mr, acc);
  }

  stage_tile7(wf, Wt[0], 16, t);

#pragma unroll
  for (int r = 0; r < TM; r++) {
    const int row = mr + r;
    float* dr = Abuf + row * PF;
    const float* njr = nbf + (size_t)(j0 + row) * 128;
#pragma unroll
    for (int c = 0; c < 2; c++) {
      const int col = cA + c;
      const float hv = (col < 128) ? dr[col]
                     : (col < 256) ? snbi[col - 128]
                                   : njr[col - 256];
      dr[col] = fmaxf(acc[r][c], 0.0f) + hv;
    }
    {
      const float hv = (cB < 128) ? dr[cB]
                     : (cB < 256) ? snbi[cB - 128]
                                  : njr[cB - 256];
      dr[cB] = fmaxf(acc[r][2], 0.0f) + hv;
    }
  }

  const int mrF = (t >> 6) * 4;
  float af[4][2];
  {
    F2 b2;
    b2.v = *(const float2*)(bfin + ct * 2);
#pragma unroll
    for (int r = 0; r < 4; r++) {
      af[r][0] = b2.f[0];
      af[r][1] = b2.f[1];
    }
  }
  for (int ft = 0; ft < 12; ft++) {
    __syncthreads();
    if (ft < 11) stage_tile7(wf + (ft + 1) * 4096, Wt[(ft + 1) & 1], 16, t);
    const float* wtc = Wt[ft & 1] + ct * 2;
    const int koff = ft * 32;
    for (int kk = 0; kk < 32; kk += 4) {
      F4 a[4];
#pragma unroll
      for (int r = 0; r < 4; r++)
        a[r].v = *(const float4*)(Abuf + (mrF + r) * PF + koff + kk);
#pragma unroll
      for (int ks = 0; ks < 4; ks++) {
        F2 wv;
        wv.v = *(const float2*)(wtc + (kk + ks) * 128);
#pragma unroll
        for (int r = 0; r < 4; r++) {
          const float ak = a[r].f[ks];
          af[r][0] += ak * wv.f[0];
          af[r][1] += ak * wv.f[1];
        }
      }
    }
  }

  {
    F2 g2, bb2;
    g2.v = *(const float2*)(lng + ct * 2);
    bb2.v = *(const float2*)(lnb + ct * 2);
#pragma unroll
    for (int r = 0; r < 4; r++) {
      float s = af[r][0] + af[r][1];
      float q = af[r][0] * af[r][0] + af[r][1] * af[r][1];
#pragma unroll
      for (int off = 1; off <= 32; off <<= 1) {
        s += __shfl_xor(s, off);
        q += __shfl_xor(q, off);
      }
      const float mu = s * (1.0f / 128.0f);
      const float var = q * (1.0f / 128.0f) - mu * mu;
      const float rstd = rsqrtf(var + 1e-5f);
      F2 o;
      o.f[0] = (af[r][0] - mu) * rstd * g2.f[0] + bb2.f[0];
      o.f[1] = (af[r][1] - mu) * rstd * g2.f[1] + bb2.f[1];
      *(float2*)(out + (size_t)(r0 + mrF + r) * 128 + ct * 2) = o.v;
    }
  }
}

// ---------------------------------------------------------------------------
// launcher — stripe count adapts to ws_size (S=8 preferred: PK stripe buffers
// 2x50MB stay L3-resident between producer and consumer)
// ---------------------------------------------------------------------------
extern "C" void kernel_launch(void* const* d_in, const int* in_sizes, int n_in,
                              void* d_out, int out_size, void* d_ws,
                              size_t ws_size, hipStream_t stream) {
  const float* node   = (const float*)d_in[0];
  const float* edge   = (const float*)d_in[1];
  const float* w_init = (const float*)d_in[2];
  const float* b_init = (const float*)d_in[3];
  const float* w_t0   = (const float*)d_in[4];
  const float* b_t0   = (const float*)d_in[5];
  const float* w_t1   = (const float*)d_in[6];
  const float* b_t1   = (const float*)d_in[7];
  const float* w_fin  = (const float*)d_in[8];
  const float* b_fin  = (const float*)d_in[9];
  const float* ln_g   = (const float*)d_in[10];
  const float* ln_b   = (const float*)d_in[11];
  float* out = (float*)d_out;
  float* ws = (float*)d_ws;

  float* nbw  = ws;             // 65536 f32
  float* Pb   = ws + 65536;     // 196608
  float* Qm   = ws + 262144;    // 196608
  float* W0pk = ws + 458752;    // 49152  (24 x 4 x 2 x 1KB)
  float* W1pk = ws + 507904;    // 147456 (24 x 12 x 2)
  float* Wfpk = ws + 655360;    // 49152  (8 x 12 x 2)
  float* C0pk = ws + 704512;    // stripe_rows*384 f32
  // A2pk follows C0pk

  node_proj<<<512, 128, 0, stream>>>(node, w_init, b_init, nbw);
  pq_proj<<<512, 384, 0, stream>>>(nbw, w_t0, b_t0, Pb, Qm);

  int S = 0;
  long stripe_rows = 0;
  for (int s = 8; s <= 256; s *= 2) {
    long sr = 262144L / s;
    size_t need = (704512ull + 2ull * (size_t)sr * 384ull) * 4ull;
    if (need <= ws_size) { S = s; stripe_rows = sr; break; }
  }

  if (S == 0) {
    edge_fused_r7<<<8192, 512, 0, stream>>>(edge, nbw, Pb, Qm, w_t0, w_t1,
                                            b_t1, w_fin, b_fin, ln_g, ln_b,
                                            out);
    return;
  }

  float* A2pk = C0pk + (size_t)stripe_rows * 384;
  const int blocks = (int)(stripe_rows / 128);

  pack_b<<<dim3(24, 4), 64, 0, stream>>>(w_t0, 384, 4, W0pk);
  pack_b<<<dim3(24, 12), 64, 0, stream>>>(w_t1, 384, 12, W1pk);
  pack_b<<<dim3(8, 12), 64, 0, stream>>>(w_fin, 128, 12, Wfpk);

  for (int s = 0; s < S; s++) {
    const long m0 = (long)s * stripe_rows;
    gemm0_k<<<blocks, 512, 0, stream>>>(edge, W0pk, Pb, Qm, C0pk, m0);
    gemm1_k<<<blocks, 512, 0, stream>>>(C0pk, W1pk, b_t1, edge, nbw, A2pk, m0);
    gemmF_k<<<blocks, 256, 0, stream>>>(A2pk, Wfpk, b_fin, ln_g, ln_b, out,
                                        m0);
  }
}

// Round 6
// 864.771 us; speedup vs baseline: 2.5298x; 2.5298x over previous
//
#include <hip/hip_runtime.h>

// ---------------------------------------------------------------------------
// EdgeTransition — Round 11: true 2 blocks/CU via N-split + R9 dbuf schedule.
// R10 failed because grid=256 on 256 CUs -> 1 block/CU regardless of LDS;
// its single-buffered B added an exposed-latency barrier per kt (150us gemm1).
// R11: gemm0/gemm1 grid (m,nh)=(256,2): 128 rows x 192 cols per block,
// A dbuf 32K + B dbuf 48K = 80KB, one barrier per kt (R9-green schedule).
// 2D grid keeps both nh-halves of an m-tile on one XCD (256 % 8 == 0).
// gemmF: 64-row blocks, grid 512, ~51KB LDS.
// Numerics: bf16x3 split (Ah*Wh + Ah*Wl + Al*Wh), rel err ~1e-4.
// ---------------------------------------------------------------------------

typedef short sv8 __attribute__((ext_vector_type(8)));   // 8 bf16 (4 VGPR)
typedef float f32x4 __attribute__((ext_vector_type(4))); // MFMA acc

union F8U { float4 v4[2]; float f[8]; };

__device__ __forceinline__ void async_cp16(const void* g, void* l) {
  __builtin_amdgcn_global_load_lds(
      (const __attribute__((address_space(1))) void*)g,
      (__attribute__((address_space(3))) void*)l, 16, 0, 0);
}

// truncation split: hi = top16(f), lo = bf16(f - hi)
__device__ __forceinline__ void split8(const float* v, sv8& hi, sv8& lo) {
#pragma unroll
  for (int i = 0; i < 8; i++) {
    unsigned u = __float_as_uint(v[i]);
    hi[i] = (short)(u >> 16);
    float fl = v[i] - __uint_as_float(u & 0xFFFF0000u);
    lo[i] = (short)(__float_as_uint(fl) >> 16);
  }
}

// ---------------------------------------------------------------------------
// pre-kernels: nb, Pb, Qm
// ---------------------------------------------------------------------------
__global__ void node_proj(const float* __restrict__ node,
                          const float* __restrict__ w,
                          const float* __restrict__ b,
                          float* __restrict__ nb) {
  __shared__ float sn[256];
  int i = blockIdx.x;
  int t = threadIdx.x;  // 128
  sn[t] = node[i * 256 + t];
  sn[t + 128] = node[i * 256 + t + 128];
  __syncthreads();
  float acc = b[t];
  for (int k = 0; k < 256; k++) acc += sn[k] * w[k * 128 + t];
  nb[i * 128 + t] = acc;
}

__global__ void pq_proj(const float* __restrict__ nb,
                        const float* __restrict__ w0,
                        const float* __restrict__ b0,
                        float* __restrict__ Pb, float* __restrict__ Qm) {
  __shared__ float sn[128];
  const int j = blockIdx.x, t = threadIdx.x;  // 384
  if (t < 128) sn[t] = nb[j * 128 + t];
  __syncthreads();
  float ap = b0[t], aq = 0.0f;
  for (int k = 0; k < 128; k++) {
    const float nk = sn[k];
    ap += nk * w0[(128 + k) * 384 + t];
    aq += nk * w0[(256 + k) * 384 + t];
  }
  Pb[j * 384 + t] = ap;
  Qm[j * 384 + t] = aq;
}

// ---------------------------------------------------------------------------
// pack W (K x N row-major, f32) -> PK split tiles [nt][kt][2][1KB]
// tile (nt,kt): lane l holds B[k = kt*32+(l>>4)*8+i][n = nt*16+(l&15)]
// ---------------------------------------------------------------------------
__global__ void pack_b(const float* __restrict__ W, int N, int NKT,
                       float* __restrict__ dst) {
  const int nt = blockIdx.x, kt = blockIdx.y, l = threadIdx.x;  // 64 thr
  const int n = nt * 16 + (l & 15);
  const int k0 = kt * 32 + ((l >> 4) * 8);
  float v[8];
#pragma unroll
  for (int i = 0; i < 8; i++) v[i] = W[(size_t)(k0 + i) * N + n];
  sv8 hi, lo;
  split8(v, hi, lo);
  char* base = (char*)dst + (size_t)((nt * NKT + kt) * 2) * 1024;
  *(sv8*)(base + l * 16) = hi;
  *(sv8*)(base + 1024 + l * 16) = lo;
}

// ---------------------------------------------------------------------------
// staging helpers — LDS dest wave-uniform; HW adds lane*16.
// ---------------------------------------------------------------------------
// E (f32 [m][128]) -> f32 slab [row 0..127][32k], 16B chunk (row,q) holds
// global chunk (q ^ (row&7)).
__device__ __forceinline__ void stage_e(const float* E, long mblk, int kt,
                                        char* dst, int wid, int lane) {
#pragma unroll
  for (int q = 0; q < 2; q++) {
    int c = wid * 2 + q;  // 0..15
    int row = c * 8 + (lane >> 3);
    int kb = ((lane & 7) * 16) ^ ((row & 7) << 4);
    const char* src =
        (const char*)E + (size_t)(mblk + row) * 512 + (size_t)kt * 128 + kb;
    async_cp16(src, dst + c * 1024);
  }
}

// A PK tiles: PW chunks per wave; dst tile idx = chunk idx (mt*2+split)
template <int PW>
__device__ __forceinline__ void stage_apk(const float* Apk, long mt0, int NKT,
                                          int kt, char* dst, int wid,
                                          int lane) {
#pragma unroll
  for (int q = 0; q < PW; q++) {
    int idx = wid * PW + q;
    int mt = idx >> 1, sp = idx & 1;
    const char* src = (const char*)Apk +
                      (size_t)(((mt0 + mt) * NKT + kt) * 2 + sp) * 1024 +
                      lane * 16;
    async_cp16(src, dst + idx * 1024);
  }
}

// B PK tiles with nt offset: PW chunks per wave
template <int PW>
__device__ __forceinline__ void stage_bpk(const float* Bpk, int NKT, int nt0,
                                          int kt, char* dst, int wid,
                                          int lane) {
#pragma unroll
  for (int q = 0; q < PW; q++) {
    int idx = wid * PW + q;
    int nt = nt0 + (idx >> 1), sp = idx & 1;
    const char* src = (const char*)Bpk +
                      (size_t)((nt * NKT + kt) * 2 + sp) * 1024 + lane * 16;
    async_cp16(src, dst + idx * 1024);
  }
}

#define MFMA __builtin_amdgcn_mfma_f32_16x16x32_bf16

// ---------------------------------------------------------------------------
// gemm0: C0pk = relu(E@W0pk + Pb[i] + Qm[j])  [128 rows x 192 cols per block]
// grid (m, nh). LDS: A dbuf 0/16K, B dbuf 32K/56K (24K each) = 80KB.
// ---------------------------------------------------------------------------
__global__ __launch_bounds__(512, 4) void gemm0_k(
    const float* __restrict__ E, const float* __restrict__ W0pk,
    const float* __restrict__ Pb, const float* __restrict__ Qm,
    float* __restrict__ C0pk, long m0) {
  __shared__ __align__(16) char sm[81920];
  const int t = threadIdx.x, lane = t & 63, wid = t >> 6;
  const int rb = wid >> 2, cb = wid & 3;
  const int mb = blockIdx.x, nh = blockIdx.y;
  const long mblk = m0 + (long)mb * 128;
  const int i_node = (int)(mblk >> 9);

  f32x4 acc[4][3] = {};

  stage_e(E, mblk, 0, sm, wid, lane);
  stage_bpk<3>(W0pk, 4, nh * 12, 0, sm + 32768, wid, lane);
  __syncthreads();

  for (int kt = 0; kt < 4; kt++) {
    if (kt < 3) {
      stage_e(E, mblk, kt + 1, sm + ((kt + 1) & 1) * 16384, wid, lane);
      stage_bpk<3>(W0pk, 4, nh * 12, kt + 1,
                   sm + 32768 + ((kt + 1) & 1) * 24576, wid, lane);
    }
    const char* sA = sm + (kt & 1) * 16384;
    const char* sB = sm + 32768 + (kt & 1) * 24576;
    sv8 ah[4], al[4], bh[3], bl[3];
#pragma unroll
    for (int rt = 0; rt < 4; rt++) {
      int row = rb * 64 + rt * 16 + (lane & 15);
      int c0 = (lane >> 4) * 32;
      F8U v;
      v.v4[0] = *(const float4*)(sA + row * 128 + (c0 ^ ((row & 7) << 4)));
      v.v4[1] =
          *(const float4*)(sA + row * 128 + ((c0 + 16) ^ ((row & 7) << 4)));
      split8(v.f, ah[rt], al[rt]);
    }
#pragma unroll
    for (int nt = 0; nt < 3; nt++) {
      int lt = cb * 3 + nt;
      bh[nt] = *(const sv8*)(sB + lt * 2048 + lane * 16);
      bl[nt] = *(const sv8*)(sB + lt * 2048 + 1024 + lane * 16);
    }
#pragma unroll
    for (int rt = 0; rt < 4; rt++)
#pragma unroll
      for (int nt = 0; nt < 3; nt++) {
        acc[rt][nt] = MFMA(ah[rt], bh[nt], acc[rt][nt], 0, 0, 0);
        acc[rt][nt] = MFMA(ah[rt], bl[nt], acc[rt][nt], 0, 0, 0);
        acc[rt][nt] = MFMA(al[rt], bh[nt], acc[rt][nt], 0, 0, 0);
      }
    __syncthreads();
  }

  // ---- epilogue: wave-private scratch rounds (alias staging LDS) ----
  float* scr = (float*)(sm + wid * 10240);  // 32x52 f32 = 6656B per wave
  const int row32r = lane & 31;
#pragma unroll
  for (int rh = 0; rh < 2; rh++) {
#pragma unroll
    for (int rt2 = 0; rt2 < 2; rt2++)
#pragma unroll
      for (int ntl = 0; ntl < 3; ntl++)
#pragma unroll
        for (int rg = 0; rg < 4; rg++) {
          int row32 = rt2 * 16 + (lane >> 4) * 4 + rg;
          scr[row32 * 52 + ntl * 16 + (lane & 15)] =
              acc[rh * 2 + rt2][ntl][rg];
        }
    const int rowb = rb * 64 + rh * 32 + row32r;
    const long m = mblk + rowb;
    const int j = (int)(m & 511);
#pragma unroll
    for (int qq = 0; qq < 3; qq++) {
      const int cloc = ((lane >> 5) * 3 + qq) * 8;
      const int colg = nh * 192 + cb * 48 + cloc;
      F8U v;
      v.v4[0] = *(float4*)(scr + row32r * 52 + cloc);
      v.v4[1] = *(float4*)(scr + row32r * 52 + cloc + 4);
      F8U pv, qv;
      pv.v4[0] = *(const float4*)(Pb + (size_t)i_node * 384 + colg);
      pv.v4[1] = *(const float4*)(Pb + (size_t)i_node * 384 + colg + 4);
      qv.v4[0] = *(const float4*)(Qm + (size_t)j * 384 + colg);
      qv.v4[1] = *(const float4*)(Qm + (size_t)j * 384 + colg + 4);
#pragma unroll
      for (int i = 0; i < 8; i++)
        v.f[i] = fmaxf(v.f[i] + pv.f[i] + qv.f[i], 0.0f);
      sv8 hi, lo;
      split8(v.f, hi, lo);
      const long mt = (long)mb * 8 + (rowb >> 4);
      const int lane2 = (rowb & 15) | (((colg >> 3) & 3) << 4);
      char* base = (char*)C0pk + (size_t)((mt * 12 + (colg >> 5)) * 2) * 1024;
      *(sv8*)(base + lane2 * 16) = hi;
      *(sv8*)(base + 1024 + lane2 * 16) = lo;
    }
  }
}

// ---------------------------------------------------------------------------
// gemm1: A2pk = relu(C0pk@W1pk + b1) + [E | nb_i | nb_j]
// Same 80KB / (m,nh) structure; NKT=12.
// ---------------------------------------------------------------------------
__global__ __launch_bounds__(512, 4) void gemm1_k(
    const float* __restrict__ C0pk, const float* __restrict__ W1pk,
    const float* __restrict__ b1, const float* __restrict__ E,
    const float* __restrict__ nb, float* __restrict__ A2pk, long m0) {
  __shared__ __align__(16) char sm[81920];
  const int t = threadIdx.x, lane = t & 63, wid = t >> 6;
  const int rb = wid >> 2, cb = wid & 3;
  const int mb = blockIdx.x, nh = blockIdx.y;
  const long mblk = m0 + (long)mb * 128;
  const int i_node = (int)(mblk >> 9);
  const long mt0 = (long)mb * 8;

  f32x4 acc[4][3] = {};

  stage_apk<2>(C0pk, mt0, 12, 0, sm, wid, lane);
  stage_bpk<3>(W1pk, 12, nh * 12, 0, sm + 32768, wid, lane);
  __syncthreads();

  for (int kt = 0; kt < 12; kt++) {
    if (kt < 11) {
      stage_apk<2>(C0pk, mt0, 12, kt + 1, sm + ((kt + 1) & 1) * 16384, wid,
                   lane);
      stage_bpk<3>(W1pk, 12, nh * 12, kt + 1,
                   sm + 32768 + ((kt + 1) & 1) * 24576, wid, lane);
    }
    const char* sA = sm + (kt & 1) * 16384;
    const char* sB = sm + 32768 + (kt & 1) * 24576;
    sv8 ah[4], al[4], bh[3], bl[3];
#pragma unroll
    for (int rt = 0; rt < 4; rt++) {
      int mtl = rb * 4 + rt;
      ah[rt] = *(const sv8*)(sA + mtl * 2048 + lane * 16);
      al[rt] = *(const sv8*)(sA + mtl * 2048 + 1024 + lane * 16);
    }
#pragma unroll
    for (int nt = 0; nt < 3; nt++) {
      int lt = cb * 3 + nt;
      bh[nt] = *(const sv8*)(sB + lt * 2048 + lane * 16);
      bl[nt] = *(const sv8*)(sB + lt * 2048 + 1024 + lane * 16);
    }
#pragma unroll
    for (int rt = 0; rt < 4; rt++)
#pragma unroll
      for (int nt = 0; nt < 3; nt++) {
        acc[rt][nt] = MFMA(ah[rt], bh[nt], acc[rt][nt], 0, 0, 0);
        acc[rt][nt] = MFMA(ah[rt], bl[nt], acc[rt][nt], 0, 0, 0);
        acc[rt][nt] = MFMA(al[rt], bh[nt], acc[rt][nt], 0, 0, 0);
      }
    __syncthreads();
  }

  // ---- epilogue ----
  float* scr = (float*)(sm + wid * 10240);
  const int row32r = lane & 31;
#pragma unroll
  for (int rh = 0; rh < 2; rh++) {
#pragma unroll
    for (int rt2 = 0; rt2 < 2; rt2++)
#pragma unroll
      for (int ntl = 0; ntl < 3; ntl++)
#pragma unroll
        for (int rg = 0; rg < 4; rg++) {
          int row32 = rt2 * 16 + (lane >> 4) * 4 + rg;
          scr[row32 * 52 + ntl * 16 + (lane & 15)] =
              acc[rh * 2 + rt2][ntl][rg];
        }
    const int rowb = rb * 64 + rh * 32 + row32r;
    const long m = mblk + rowb;
    const int j = (int)(m & 511);
#pragma unroll
    for (int qq = 0; qq < 3; qq++) {
      const int cloc = ((lane >> 5) * 3 + qq) * 8;
      const int colg = nh * 192 + cb * 48 + cloc;
      F8U v;
      v.v4[0] = *(float4*)(scr + row32r * 52 + cloc);
      v.v4[1] = *(float4*)(scr + row32r * 52 + cloc + 4);
      F8U bv, hv;
      bv.v4[0] = *(const float4*)(b1 + colg);
      bv.v4[1] = *(const float4*)(b1 + colg + 4);
      if (colg < 128) {
        hv.v4[0] = *(const float4*)(E + (size_t)m * 128 + colg);
        hv.v4[1] = *(const float4*)(E + (size_t)m * 128 + colg + 4);
      } else if (colg < 256) {
        hv.v4[0] = *(const float4*)(nb + (size_t)i_node * 128 + (colg - 128));
        hv.v4[1] =
            *(const float4*)(nb + (size_t)i_node * 128 + (colg - 128) + 4);
      } else {
        hv.v4[0] = *(const float4*)(nb + (size_t)j * 128 + (colg - 256));
        hv.v4[1] = *(const float4*)(nb + (size_t)j * 128 + (colg - 256) + 4);
      }
#pragma unroll
      for (int i = 0; i < 8; i++)
        v.f[i] = fmaxf(v.f[i] + bv.f[i], 0.0f) + hv.f[i];
      sv8 hi, lo;
      split8(v.f, hi, lo);
      const long mt = (long)mb * 8 + (rowb >> 4);
      const int lane2 = (rowb & 15) | (((colg >> 3) & 3) << 4);
      char* base = (char*)A2pk + (size_t)((mt * 12 + (colg >> 5)) * 2) * 1024;
      *(sv8*)(base + lane2 * 16) = hi;
      *(sv8*)(base + 1024 + lane2 * 16) = lo;
    }
  }
}

// ---------------------------------------------------------------------------
// gemmF: out = LN(A2pk@Wfpk + bf)   [64 rows x 128 cols per block], 4 waves
// LDS: A dbuf 0/8K, B dbuf 16K/32K, aux @49152. Grid = stripe_rows/64.
// ---------------------------------------------------------------------------
__global__ __launch_bounds__(256, 2) void gemmF_k(
    const float* __restrict__ A2pk, const float* __restrict__ Wfpk,
    const float* __restrict__ bfin, const float* __restrict__ lng,
    const float* __restrict__ lnb, float* __restrict__ out, long m0) {
  __shared__ __align__(16) char sm[52224];
  const int t = threadIdx.x, lane = t & 63, wid = t >> 6;
  const int rb = wid >> 1, cb = wid & 1;
  const long mblk = m0 + (long)blockIdx.x * 64;
  float* sG = (float*)(sm + 49152);   // 128
  float* sB = sG + 128;               // 128
  float* sBf = sG + 256;              // 128
  float* sLN = sG + 384;              // 64 rows x 4
  if (t < 128) {
    sG[t] = lng[t];
    sB[t] = lnb[t];
    sBf[t] = bfin[t];
  }

  f32x4 acc[2][4] = {};
  const long mt0 = (long)blockIdx.x * 4;
  stage_apk<2>(A2pk, mt0, 12, 0, sm, wid, lane);
  stage_bpk<4>(Wfpk, 12, 0, 0, sm + 16384, wid, lane);
  __syncthreads();

  for (int kt = 0; kt < 12; kt++) {
    const int buf = kt & 1;
    if (kt < 11) {
      stage_apk<2>(A2pk, mt0, 12, kt + 1, sm + (buf ^ 1) * 8192, wid, lane);
      stage_bpk<4>(Wfpk, 12, 0, kt + 1, sm + 16384 + (buf ^ 1) * 16384, wid,
                   lane);
    }
    const char* sA = sm + buf * 8192;
    const char* sBt = sm + 16384 + buf * 16384;
    sv8 ah[2], al[2], bh[4], bl[4];
#pragma unroll
    for (int rt = 0; rt < 2; rt++) {
      int mtl = rb * 2 + rt;
      ah[rt] = *(const sv8*)(sA + mtl * 2048 + lane * 16);
      al[rt] = *(const sv8*)(sA + mtl * 2048 + 1024 + lane * 16);
    }
#pragma unroll
    for (int nt = 0; nt < 4; nt++) {
      int gnt = cb * 4 + nt;
      bh[nt] = *(const sv8*)(sBt + gnt * 2048 + lane * 16);
      bl[nt] = *(const sv8*)(sBt + gnt * 2048 + 1024 + lane * 16);
    }
#pragma unroll
    for (int rt = 0; rt < 2; rt++)
#pragma unroll
      for (int nt = 0; nt < 4; nt++) {
        acc[rt][nt] = MFMA(ah[rt], bh[nt], acc[rt][nt], 0, 0, 0);
        acc[rt][nt] = MFMA(ah[rt], bl[nt], acc[rt][nt], 0, 0, 0);
        acc[rt][nt] = MFMA(al[rt], bh[nt], acc[rt][nt], 0, 0, 0);
      }
    __syncthreads();
  }

  // ---- LN partial sums ----
#pragma unroll
  for (int rt = 0; rt < 2; rt++)
#pragma unroll
    for (int rg = 0; rg < 4; rg++) {
      float s = 0.0f, q = 0.0f;
#pragma unroll
      for (int nt = 0; nt < 4; nt++) {
        const int col = cb * 64 + nt * 16 + (lane & 15);
        const float v = acc[rt][nt][rg] + sBf[col];
        s += v;
        q += v * v;
      }
#pragma unroll
      for (int off = 1; off <= 8; off <<= 1) {
        s += __shfl_xor(s, off);
        q += __shfl_xor(q, off);
      }
      const int row = rb * 32 + rt * 16 + (lane >> 4) * 4 + rg;
      if ((lane & 15) == 0) {
        sLN[row * 4 + cb * 2 + 0] = s;
        sLN[row * 4 + cb * 2 + 1] = q;
      }
    }
  __syncthreads();

  // ---- normalize + store ----
#pragma unroll
  for (int rt = 0; rt < 2; rt++)
#pragma unroll
    for (int rg = 0; rg < 4; rg++) {
      const int row = rb * 32 + rt * 16 + (lane >> 4) * 4 + rg;
      const float s = sLN[row * 4 + 0] + sLN[row * 4 + 2];
      const float q = sLN[row * 4 + 1] + sLN[row * 4 + 3];
      const float mu = s * (1.0f / 128.0f);
      const float var = q * (1.0f / 128.0f) - mu * mu;
      const float rstd = rsqrtf(var + 1e-5f);
      float* op = out + (size_t)(mblk + row) * 128;
#pragma unroll
      for (int nt = 0; nt < 4; nt++) {
        const int col = cb * 64 + nt * 16 + (lane & 15);
        const float v = acc[rt][nt][rg] + sBf[col];
        op[col] = (v - mu) * rstd * sG[col] + sB[col];
      }
    }
}

// ---------------------------------------------------------------------------
// Round-7 fp32 fallback (last resort, known-green)
// ---------------------------------------------------------------------------
#define ROWS 32
#define PF 388
#define TM 8
union F4 { float4 v; float f[4]; };
union F2 { float2 v; float f[2]; };

__device__ __forceinline__ void stage_tile7(const float* __restrict__ g,
                                            float* l, int nchunk, int t) {
  const int lane = t & 63, wid = t >> 6;
  for (int c = wid; c < nchunk; c += 8)
    async_cp16(g + c * 256 + lane * 4, l + c * 256);
}

__device__ __forceinline__ void trunk_tile7(const float* __restrict__ src,
                                            int koff,
                                            const float* __restrict__ wt,
                                            int cA, int cB, int mr,
                                            float acc[TM][3]) {
  for (int kk = 0; kk < 16; kk += 4) {
    F4 a[TM];
#pragma unroll
    for (int r = 0; r < TM; r++)
      a[r].v = *(const float4*)(src + (mr + r) * PF + koff + kk);
#pragma unroll
    for (int ks = 0; ks < 4; ks++) {
      const float* wrow = wt + (kk + ks) * 384;
      F2 w2;
      w2.v = *(const float2*)(wrow + cA);
      const float w1 = wrow[cB];
#pragma unroll
      for (int r = 0; r < TM; r++) {
        const float ak = a[r].f[ks];
        acc[r][0] += ak * w2.f[0];
        acc[r][1] += ak * w2.f[1];
        acc[r][2] += ak * w1;
      }
    }
  }
}

__global__ __launch_bounds__(512, 1) void edge_fused_r7(
    const float* __restrict__ edge, const float* __restrict__ nbf,
    const float* __restrict__ Pb, const float* __restrict__ Qm,
    const float* __restrict__ w0, const float* __restrict__ w1,
    const float* __restrict__ b1v, const float* __restrict__ wf,
    const float* __restrict__ bfin, const float* __restrict__ lng,
    const float* __restrict__ lnb, float* __restrict__ out) {
  __shared__ __align__(16) float Abuf[ROWS * PF];
  __shared__ __align__(16) float Bbuf[ROWS * PF];
  __shared__ __align__(16) float Wt[2][16 * 384];
  __shared__ __align__(16) float snbi[128];

  const int t = threadIdx.x;
  const int ct = t & 63;
  const int g = t >> 8;
  const int mr = ((t >> 6) & 3) * TM;
  const int cA = g * 192 + 2 * ct;
  const int cB = g * 192 + 128 + ct;
  const int r0 = blockIdx.x * ROWS;
  const int i_node = r0 >> 9, j0 = r0 & 511;

  {
    const int row = t >> 4, q = t & 15;
    const float* ep = edge + (size_t)(r0 + row) * 128 + q * 8;
    float* ap = Abuf + row * PF + q * 8;
    *(float4*)(ap + 0) = *(const float4*)(ep + 0);
    *(float4*)(ap + 4) = *(const float4*)(ep + 4);
  }
  if (t < 32)
    *(float4*)(snbi + t * 4) = *(const float4*)(nbf + i_node * 128 + t * 4);

  stage_tile7(w0, Wt[0], 24, t);

  float acc[TM][3];
  {
    const float* pr = Pb + i_node * 384;
    F2 p2;
    p2.v = *(const float2*)(pr + cA);
    const float p1 = pr[cB];
#pragma unroll
    for (int r = 0; r < TM; r++) {
      const float* qr = Qm + (size_t)(j0 + mr + r) * 384;
      F2 q2;
      q2.v = *(const float2*)(qr + cA);
      acc[r][0] = p2.f[0] + q2.f[0];
      acc[r][1] = p2.f[1] + q2.f[1];
      acc[r][2] = p1 + qr[cB];
    }
  }

  for (int kt = 0; kt < 8; kt++) {
    __syncthreads();
    if (kt < 7) stage_tile7(w0 + (kt + 1) * 6144, Wt[(kt + 1) & 1], 24, t);
    trunk_tile7(Abuf, kt * 16, Wt[kt & 1], cA, cB, mr, acc);
  }

  stage_tile7(w1, Wt[0], 24, t);
#pragma unroll
  for (int r = 0; r < TM; r++) {
    float* dr = Bbuf + (mr + r) * PF;
    F2 e2;
    e2.f[0] = fmaxf(acc[r][0], 0.0f);
    e2.f[1] = fmaxf(acc[r][1], 0.0f);
    *(float2*)(dr + cA) = e2.v;
    dr[cB] = fmaxf(acc[r][2], 0.0f);
  }

  {
    F2 c2;
    c2.v = *(const float2*)(b1v + cA);
    const float c1 = b1v[cB];
#pragma unroll
    for (int r = 0; r < TM; r++) {
      acc[r][0] = c2.f[0];
      acc[r][1] = c2.f[1];
      acc[r][2] = c1;
    }
  }

  for (int kt = 0; kt < 24; kt++) {
    __syncthreads();
    if (kt < 23) stage_tile7(w1 + (kt + 1) * 6144, Wt[(kt + 1) & 1], 24, t);
    trunk_tile7(Bbuf, kt * 16, Wt[kt & 1], cA, cB, mr, acc);
  }

  stage_tile7(wf, Wt[0], 16, t);

#pragma unroll
  for (int r = 0; r < TM; r++) {
    const int row = mr + r;
    float* dr = Abuf + row * PF;
    const float* njr = nbf + (size_t)(j0 + row) * 128;
#pragma unroll
    for (int c = 0; c < 2; c++) {
      const int col = cA + c;
      const float hv = (col < 128) ? dr[col]
                     : (col < 256) ? snbi[col - 128]
                                   : njr[col - 256];
      dr[col] = fmaxf(acc[r][c], 0.0f) + hv;
    }
    {
      const float hv = (cB < 128) ? dr[cB]
                     : (cB < 256) ? snbi[cB - 128]
                                  : njr[cB - 256];
      dr[cB] = fmaxf(acc[r][2], 0.0f) + hv;
    }
  }

  const int mrF = (t >> 6) * 4;
  float af[4][2];
  {
    F2 b2;
    b2.v = *(const float2*)(bfin + ct * 2);
#pragma unroll
    for (int r = 0; r < 4; r++) {
      af[r][0] = b2.f[0];
      af[r][1] = b2.f[1];
    }
  }
  for (int ft = 0; ft < 12; ft++) {
    __syncthreads();
    if (ft < 11) stage_tile7(wf + (ft + 1) * 4096, Wt[(ft + 1) & 1], 16, t);
    const float* wtc = Wt[ft & 1] + ct * 2;
    const int koff = ft * 32;
    for (int kk = 0; kk < 32; kk += 4) {
      F4 a[4];
#pragma unroll
      for (int r = 0; r < 4; r++)
        a[r].v = *(const float4*)(Abuf + (mrF + r) * PF + koff + kk);
#pragma unroll
      for (int ks = 0; ks < 4; ks++) {
        F2 wv;
        wv.v = *(const float2*)(wtc + (kk + ks) * 128);
#pragma unroll
        for (int r = 0; r < 4; r++) {
          const float ak = a[r].f[ks];
          af[r][0] += ak * wv.f[0];
          af[r][1] += ak * wv.f[1];
        }
      }
    }
  }

  {
    F2 g2, bb2;
    g2.v = *(const float2*)(lng + ct * 2);
    bb2.v = *(const float2*)(lnb + ct * 2);
#pragma unroll
    for (int r = 0; r < 4; r++) {
      float s = af[r][0] + af[r][1];
      float q = af[r][0] * af[r][0] + af[r][1] * af[r][1];
#pragma unroll
      for (int off = 1; off <= 32; off <<= 1) {
        s += __shfl_xor(s, off);
        q += __shfl_xor(q, off);
      }
      const float mu = s * (1.0f / 128.0f);
      const float var = q * (1.0f / 128.0f) - mu * mu;
      const float rstd = rsqrtf(var + 1e-5f);
      F2 o;
      o.f[0] = (af[r][0] - mu) * rstd * g2.f[0] + bb2.f[0];
      o.f[1] = (af[r][1] - mu) * rstd * g2.f[1] + bb2.f[1];
      *(float2*)(out + (size_t)(r0 + mrF + r) * 128 + ct * 2) = o.v;
    }
  }
}

// ---------------------------------------------------------------------------
// launcher — stripe count adapts to ws_size (S=8 preferred)
// ---------------------------------------------------------------------------
extern "C" void kernel_launch(void* const* d_in, const int* in_sizes, int n_in,
                              void* d_out, int out_size, void* d_ws,
                              size_t ws_size, hipStream_t stream) {
  const float* node   = (const float*)d_in[0];
  const float* edge   = (const float*)d_in[1];
  const float* w_init = (const float*)d_in[2];
  const float* b_init = (const float*)d_in[3];
  const float* w_t0   = (const float*)d_in[4];
  const float* b_t0   = (const float*)d_in[5];
  const float* w_t1   = (const float*)d_in[6];
  const float* b_t1   = (const float*)d_in[7];
  const float* w_fin  = (const float*)d_in[8];
  const float* b_fin  = (const float*)d_in[9];
  const float* ln_g   = (const float*)d_in[10];
  const float* ln_b   = (const float*)d_in[11];
  float* out = (float*)d_out;
  float* ws = (float*)d_ws;

  float* nbw  = ws;             // 65536 f32
  float* Pb   = ws + 65536;     // 196608
  float* Qm   = ws + 262144;    // 196608
  float* W0pk = ws + 458752;    // 49152  (24 x 4 x 2 x 1KB)
  float* W1pk = ws + 507904;    // 147456 (24 x 12 x 2)
  float* Wfpk = ws + 655360;    // 49152  (8 x 12 x 2)
  float* C0pk = ws + 704512;    // stripe_rows*384 f32
  // A2pk follows C0pk

  node_proj<<<512, 128, 0, stream>>>(node, w_init, b_init, nbw);
  pq_proj<<<512, 384, 0, stream>>>(nbw, w_t0, b_t0, Pb, Qm);

  int S = 0;
  long stripe_rows = 0;
  for (int s = 8; s <= 256; s *= 2) {
    long sr = 262144L / s;
    size_t need = (704512ull + 2ull * (size_t)sr * 384ull) * 4ull;
    if (need <= ws_size) { S = s; stripe_rows = sr; break; }
  }

  if (S == 0) {
    edge_fused_r7<<<8192, 512, 0, stream>>>(edge, nbw, Pb, Qm, w_t0, w_t1,
                                            b_t1, w_fin, b_fin, ln_g, ln_b,
                                            out);
    return;
  }

  float* A2pk = C0pk + (size_t)stripe_rows * 384;
  const int bx = (int)(stripe_rows / 128);

  pack_b<<<dim3(24, 4), 64, 0, stream>>>(w_t0, 384, 4, W0pk);
  pack_b<<<dim3(24, 12), 64, 0, stream>>>(w_t1, 384, 12, W1pk);
  pack_b<<<dim3(8, 12), 64, 0, stream>>>(w_fin, 128, 12, Wfpk);

  for (int s = 0; s < S; s++) {
    const long m0 = (long)s * stripe_rows;
    gemm0_k<<<dim3(bx, 2), 512, 0, stream>>>(edge, W0pk, Pb, Qm, C0pk, m0);
    gemm1_k<<<dim3(bx, 2), 512, 0, stream>>>(C0pk, W1pk, b_t1, edge, nbw,
                                             A2pk, m0);
    gemmF_k<<<bx * 2, 256, 0, stream>>>(A2pk, Wfpk, b_fin, ln_g, ln_b, out,
                                        m0);
  }
}